// Round 6
// baseline (561.471 us; speedup 1.0000x reference)
//
#include <hip/hip_runtime.h>
#include <math.h>

// Problem constants
#define N_IMG 128
#define IC 8
#define IH 128
#define IW 128
#define OC 64
#define OH 126
#define OW 126
#define NG 16
#define CPG 4          // channels per group
#define PH 31
#define PW 31
#define GN_EPS 1e-5f

#define STRIPS 16      // 16 strips x 8 conv rows cover conv rows 0..125 (+mask)
#define LROWS 10       // input rows staged per strip (8 + 2 halo)
#define LPITCH 132     // row pitch in floats (128 + pad to de-phase banks)

// One block per (n, group). Strip-mined single conv pass:
//  - per strip: stage 10 input rows x 8 ic into LDS (coalesced float4),
//    then each thread computes one (conv row, 4-col group) x 4 ch task with
//    ONLY LDS reads in the inner loop (removes the per-(ic,kh) global-load
//    latency that pinned VALUBusy at ~54% in R2-R5).
//  - GN stats (sum/sumsq) accumulated per thread across all conv outputs.
//  - Pool via max-before-affine trick (slope sign known before stats since
//    rstd>0): per-task col-max -> pmbuf in LDS -> owner thread's registers.
// Blocks swizzled so all 16 groups of image n land on XCD n%8 back-to-back.
__launch_bounds__(256, 3)
__global__ void fused_conv_gn_pool_kernel(const float* __restrict__ x,
                                          const float* __restrict__ conv_w,
                                          const float* __restrict__ conv_b,
                                          const float* __restrict__ gn_w,
                                          const float* __restrict__ gn_b,
                                          const float* __restrict__ scale,
                                          float* __restrict__ out) {
    // XCD swizzle: XCD(b) = b % 8 (round-robin dispatch).
    const int b = blockIdx.x;
    const int xcd = b & 7;
    const int slot = b >> 3;           // 0..255
    const int g = slot & 15;
    const int n = xcd + 8 * (slot >> 4);
    const int tid = threadIdx.x;

    __shared__ float xs[IC * LROWS * LPITCH];    // 10560 floats = 41.25 KB
    __shared__ float wlds[IC * 3 * 3 * CPG];     // 288 floats, [ic][kh][kw][ch]
    __shared__ float pmbuf[8 * 32 * CPG];        // [hr][cg][ch], 4 KB
    __shared__ float red[8];
    __shared__ float stats[2];

    // Stage weights transposed to [ic][kh][kw][ch].
    for (int t = tid; t < IC * 3 * 3 * CPG; t += 256) {
        int ch = t & 3;
        int r = t >> 2;                          // ic*9 + kh*3 + kw
        wlds[t] = conv_w[(g * CPG + ch) * (IC * 9) + r];
    }
    float bias[CPG], sgnf[CPG];
#pragma unroll
    for (int ch = 0; ch < CPG; ch++) {
        int c = g * CPG + ch;
        bias[ch] = conv_b[c];
        sgnf[ch] = (gn_w[c] * scale[c] >= 0.f) ? 1.f : -1.f;
    }

    const float* xb = x + (size_t)n * (IC * IH * IW);

    const int hr = tid >> 5;        // 0..7: conv row within strip
    const int cg = tid & 31;        // 0..31: 4-col group (cg=31 -> 2 valid cols)
    const bool cg_edge = (cg == 31);

    float s = 0.f, ss = 0.f;
    float pm[4][CPG];               // persistent pooled extreme per owned cell
#pragma unroll
    for (int ci = 0; ci < 4; ci++)
#pragma unroll
        for (int ch = 0; ch < CPG; ch++) pm[ci][ch] = -INFINITY;

#pragma unroll 1
    for (int t = 0; t < STRIPS; t++) {
        const int row0 = 8 * t;
        __syncthreads();   // xs/pmbuf from previous strip fully consumed

        // ---- Stage input rows row0..row0+9 (all 8 ic) into LDS ----
#pragma unroll
        for (int k = 0; k < LROWS; k++) {
            int idx = tid + k * 256;             // 0..2559
            int icd = idx >> 5;                  // ic*LROWS + d
            int col4 = idx & 31;
            int ic = icd / LROWS;
            int d = icd - ic * LROWS;
            int gr = row0 + d;
            float4 v = make_float4(0.f, 0.f, 0.f, 0.f);
            if (gr < IH)
                v = *(const float4*)(xb + ic * (IH * IW) + gr * IW + col4 * 4);
            *(float4*)&xs[icd * LPITCH + col4 * 4] = v;
        }
        __syncthreads();

        // ---- Compute task: conv row oh = row0+hr, cols 4cg..4cg+3, 4 ch ----
        const int oh = row0 + hr;
        if (oh < OH) {
            float acc[4][CPG];
#pragma unroll
            for (int j = 0; j < 4; j++)
#pragma unroll
                for (int ch = 0; ch < CPG; ch++) acc[j][ch] = bias[ch];

#pragma unroll 2
            for (int ic = 0; ic < IC; ic++) {
#pragma unroll
                for (int kh = 0; kh < 3; kh++) {
                    const float* xr = &xs[(ic * LROWS + hr + kh) * LPITCH + cg * 4];
                    float4 f4 = *(const float4*)xr;
                    float v0 = f4.x, v1 = f4.y, v2 = f4.z, v3 = f4.w;
                    float v4 = 0.f, v5 = 0.f;
                    if (!cg_edge) {
                        float2 f2 = *(const float2*)(xr + 4);
                        v4 = f2.x; v5 = f2.y;
                    }
                    const float* wk = &wlds[(ic * 3 + kh) * 12];
                    float wr[12];
#pragma unroll
                    for (int q = 0; q < 12; q++) wr[q] = wk[q];
#pragma unroll
                    for (int ch = 0; ch < CPG; ch++) {
                        float w0 = wr[0 * 4 + ch];
                        float w1 = wr[1 * 4 + ch];
                        float w2 = wr[2 * 4 + ch];
                        acc[0][ch] = fmaf(v0, w0, fmaf(v1, w1, fmaf(v2, w2, acc[0][ch])));
                        acc[1][ch] = fmaf(v1, w0, fmaf(v2, w1, fmaf(v3, w2, acc[1][ch])));
                        acc[2][ch] = fmaf(v2, w0, fmaf(v3, w1, fmaf(v4, w2, acc[2][ch])));
                        acc[3][ch] = fmaf(v3, w0, fmaf(v4, w1, fmaf(v5, w2, acc[3][ch])));
                    }
                }
            }

            // Stats + per-row col-max (cg=31: only cols 124,125 are valid)
            float taskpm[CPG];
#pragma unroll
            for (int ch = 0; ch < CPG; ch++) taskpm[ch] = -INFINITY;
            int jmax = cg_edge ? 2 : 4;
#pragma unroll
            for (int j = 0; j < 4; j++) {
                if (j < jmax) {
#pragma unroll
                    for (int ch = 0; ch < CPG; ch++) {
                        float v = acc[j][ch];
                        s += v;
                        ss = fmaf(v, v, ss);
                        taskpm[ch] = fmaxf(taskpm[ch], v * sgnf[ch]);
                    }
                }
            }
#pragma unroll
            for (int ch = 0; ch < CPG; ch++)
                pmbuf[(hr * 32 + cg) * CPG + ch] = taskpm[ch];
        }
        __syncthreads();

        // ---- Fold this strip's row-maxes into owner threads' pool regs ----
#pragma unroll
        for (int ci = 0; ci < 4; ci++) {
            int cell = tid + ci * 256;
            if (cell < PH * PW) {
                int ph = cell / PW;
                int pw = cell - ph * PW;
                if ((ph >> 1) == t) {
                    int hb = (ph & 1) * 4;       // conv-row base within strip
#pragma unroll
                    for (int k = 0; k < 4; k++)
#pragma unroll
                        for (int ch = 0; ch < CPG; ch++)
                            pm[ci][ch] = fmaxf(pm[ci][ch],
                                               pmbuf[((hb + k) * 32 + pw) * CPG + ch]);
                }
            }
        }
    }

    // ---- Block reduction for GN stats ----
#pragma unroll
    for (int off = 32; off > 0; off >>= 1) {
        s  += __shfl_down(s, off, 64);
        ss += __shfl_down(ss, off, 64);
    }
    int wave = tid >> 6;
    if ((tid & 63) == 0) { red[wave] = s; red[4 + wave] = ss; }
    __syncthreads();
    if (tid == 0) {
        float S  = red[0] + red[1] + red[2] + red[3];
        float SS = red[4] + red[5] + red[6] + red[7];
        const float inv_count = 1.f / (float)(CPG * OH * OW);
        float mean = S * inv_count;
        float var = SS * inv_count - mean * mean;
        if (var < 0.f) var = 0.f;
        stats[0] = mean;
        stats[1] = rsqrtf(var + GN_EPS);
    }
    __syncthreads();
    const float mean = stats[0];
    const float rstd = stats[1];

    // Fused affine for the pooled extreme: out = a2*M + b2  (a2 >= 0)
    float a2[CPG], b2[CPG];
#pragma unroll
    for (int ch = 0; ch < CPG; ch++) {
        int c = g * CPG + ch;
        float gw = gn_w[c], sc = scale[c];
        a2[ch] = rstd * fabsf(gw * sc);
        b2[ch] = (gn_b[c] - mean * rstd * gw) * sc;
    }

    // ---- Write pooled, clamped output ----
#pragma unroll
    for (int ci = 0; ci < 4; ci++) {
        int cell = tid + ci * 256;
        if (cell < PH * PW) {
            int ph = cell / PW;
            int pw = cell - ph * PW;
#pragma unroll
            for (int ch = 0; ch < CPG; ch++) {
                int c = g * CPG + ch;
                float v = fmaf(a2[ch], pm[ci][ch], b2[ch]);
                v = fminf(fmaxf(v, 0.f), 1.f);
                out[(((size_t)n * OC + c) * PH + ph) * PW + pw] = v;
            }
        }
    }
}

extern "C" void kernel_launch(void* const* d_in, const int* in_sizes, int n_in,
                              void* d_out, int out_size, void* d_ws, size_t ws_size,
                              hipStream_t stream) {
    const float* x      = (const float*)d_in[0];
    const float* conv_w = (const float*)d_in[1];
    const float* conv_b = (const float*)d_in[2];
    const float* gn_w   = (const float*)d_in[3];
    const float* gn_b   = (const float*)d_in[4];
    const float* scale  = (const float*)d_in[5];
    float* out = (float*)d_out;

    dim3 grid(N_IMG * NG);   // one block per (n, group), XCD-swizzled in-kernel
    dim3 block(256);
    hipLaunchKernelGGL(fused_conv_gn_pool_kernel, grid, block, 0, stream,
                       x, conv_w, conv_b, gn_w, gn_b, scale, out);
}